// Round 6
// baseline (245.578 us; speedup 1.0000x reference)
//
#include <hip/hip_runtime.h>
#include <stdint.h>

#define HD   1024
#define LD   4096
#define BATCH 4
#define KLEN 8192           // 2*L
#define LAM  0.1f
#define TAP_CAP 65536
#define NT   16             // K tiles: 1024 / 64

typedef __attribute__((ext_vector_type(8))) short short8x;
typedef __attribute__((ext_vector_type(4))) float float4x;

struct Tap { int hd; float v; };

__device__ inline unsigned short f2bf(float x) {
    union { float f; uint32_t u; } v; v.f = x;
    uint32_t u = v.u;
    u += 0x7fffu + ((u >> 16) & 1u);
    return (unsigned short)(u >> 16);
}

__device__ inline void gload16(const void* g, void* l) {
    __builtin_amdgcn_global_load_lds(
        (const __attribute__((address_space(1))) void*)g,
        (__attribute__((address_space(3))) void*)l,
        16, 0, 0);
}

__device__ inline float silu_f(float x) { return x / (1.0f + __expf(-x)); }

// ---------------------------------------------------------------------------
// k_pv: three independent jobs fused as disjoint block ranges:
//   bid <  1024: W fp32->bf16
//   bid <  3072: kernel tap scan (+ per-64h-group tap counters for k_fix)
//   bid >= 3072: Vt build, TAPLESS path: silu(u*D) -> (B*L, H) bf16.
// Tap corrections (rare; zero on bench data) are applied by k_fix afterward.
// ---------------------------------------------------------------------------
__global__ __launch_bounds__(256) void k_pv(const float* __restrict__ u,
                                            const float* __restrict__ kern,
                                            const float* __restrict__ Dv,
                                            const float* __restrict__ W,
                                            int* __restrict__ ntaps,
                                            int* __restrict__ cnt64,
                                            Tap* __restrict__ taps,
                                            unsigned short* __restrict__ Wbf,
                                            unsigned short* __restrict__ Vt) {
    __shared__ float T[64 * 65];                 // used by vt blocks only
    int tid = threadIdx.x;
    int bid = blockIdx.x;

    if (bid < 1024) {                            // ---- W -> bf16 ----
        int i = bid * 256 + tid;
        const float4* w4 = (const float4*)W;
        float4 a = w4[i * 2], b = w4[i * 2 + 1];
        short8x o;
        o[0] = (short)f2bf(a.x); o[1] = (short)f2bf(a.y);
        o[2] = (short)f2bf(a.z); o[3] = (short)f2bf(a.w);
        o[4] = (short)f2bf(b.x); o[5] = (short)f2bf(b.y);
        o[6] = (short)f2bf(b.z); o[7] = (short)f2bf(b.w);
        *(short8x*)(Wbf + (int64_t)i * 8) = o;
        return;
    }
    if (bid < 3072) {                            // ---- kernel tap scan ----
        int bs = bid - 1024;
        const float4* k4 = (const float4*)kern;
        int64_t total4 = (int64_t)HD * KLEN / 4;
        int64_t stride = (int64_t)2048 * 256;
        for (int64_t i = (int64_t)bs * 256 + tid; i < total4; i += stride) {
            float4 v = k4[i];
            float vals[4] = {v.x, v.y, v.z, v.w};
#pragma unroll
            for (int j = 0; j < 4; j++) {
                float a = fabsf(vals[j]) - LAM;
                if (a > 0.0f) {
                    int e = (int)(i * 4 + j);
                    int slot = atomicAdd(ntaps, 1);
                    if (slot < TAP_CAP) { taps[slot].hd = e; taps[slot].v = copysignf(a, vals[j]); }
                    atomicAdd(&cnt64[e >> 19], 1);   // h-group = (e>>13)>>6
                }
            }
        }
        return;
    }
    // ---- Vt build, tapless ----
    int job = bid - 3072;                        // 4096 jobs
    int lt = (job & 63) * 64;
    int ht = ((job >> 6) & 15) * 64;
    int b  = job >> 10;
    int lq = tid & 15;
    int hh = tid >> 4;
#pragma unroll
    for (int r = 0; r < 4; r++) {
        int h = hh + r * 16;
        int hg = ht + h;
        int64_t base = ((int64_t)b * HD + hg) * LD + lt + lq * 4;
        float4 v = *(const float4*)(u + base);
        float d = Dv[hg];
        int p = h * 65 + lq * 4;
        T[p]     = silu_f(v.x * d);
        T[p + 1] = silu_f(v.y * d);
        T[p + 2] = silu_f(v.z * d);
        T[p + 3] = silu_f(v.w * d);
    }
    __syncthreads();
    int h8 = (tid & 7) * 8;
    int nb = tid >> 3;
#pragma unroll
    for (int p = 0; p < 2; p++) {
        int nl = nb + p * 32;
        short8x o;
#pragma unroll
        for (int j = 0; j < 8; j++) o[j] = (short)f2bf(T[(h8 + j) * 65 + nl]);
        int64_t n = (int64_t)b * LD + lt + nl;
        *(short8x*)(Vt + n * HD + ht + h8) = o;
    }
}

// ---------------------------------------------------------------------------
// k_fix: recompute Vt tiles for h-groups that have taps (full conv path).
// Early-exits on the per-group counter -> ~0 cost when no taps (bench data).
// ---------------------------------------------------------------------------
__global__ __launch_bounds__(256) void k_fix(const float* __restrict__ u,
                                             const float* __restrict__ Dv,
                                             const int* __restrict__ ntaps_p,
                                             const int* __restrict__ cnt64,
                                             const Tap* __restrict__ taps,
                                             unsigned short* __restrict__ Vt) {
    __shared__ float T[64 * 65];
    int g = blockIdx.x;
    if (cnt64[g] == 0) return;
    int nt = min(*ntaps_p, TAP_CAP);
    int ht = g * 64;
    int lt = blockIdx.y * 64;
    int b  = blockIdx.z;
    int tid = threadIdx.x;
    int lq = tid & 15;
    int hh = tid >> 4;
#pragma unroll
    for (int r = 0; r < 4; r++) {
        int h = hh + r * 16;
        int hg = ht + h;
        int64_t base = ((int64_t)b * HD + hg) * LD + lt + lq * 4;
        float4 v = *(const float4*)(u + base);
        float d = Dv[hg];
        float acc[4] = {v.x * d, v.y * d, v.z * d, v.w * d};
        const float* ub = u + ((int64_t)b * HD + hg) * LD;
        for (int j = 0; j < nt; j++) {
            int hd = taps[j].hd;
            if ((hd >> 13) != hg) continue;
            int dly = hd & (KLEN - 1);
#pragma unroll
            for (int e = 0; e < 4; e++) {
                int t = lt + lq * 4 + e;
                int s = t - dly;
                if (s < 0) s += KLEN;
                if (s < LD) acc[e] += taps[j].v * ub[s];
            }
        }
        int p = h * 65 + lq * 4;
        T[p]     = silu_f(acc[0]);
        T[p + 1] = silu_f(acc[1]);
        T[p + 2] = silu_f(acc[2]);
        T[p + 3] = silu_f(acc[3]);
    }
    __syncthreads();
    int h8 = (tid & 7) * 8;
    int nb = tid >> 3;
#pragma unroll
    for (int p = 0; p < 2; p++) {
        int nl = nb + p * 32;
        short8x o;
#pragma unroll
        for (int j = 0; j < 8; j++) o[j] = (short)f2bf(T[(h8 + j) * 65 + nl]);
        int64_t n = (int64_t)b * LD + lt + nl;
        *(short8x*)(Vt + n * HD + ht + h8) = o;
    }
}

// ---------------- GEMM + GLU: 256x256 tile, BK=64, 16 WAVES ----------------
// Z = Wbf(2048x1024) * Vt^T(1024x16384); out = (z_a+b_a)*sigmoid(z_g+b_g)
// OCCUPANCY round: all prior rounds ran 2 waves/SIMD (acc 128 f32/lane ->
// ~230-260 unified regs). Here 16 waves (1024 thr), a/g split ACROSS waves:
// wm in {0,1} -> a-rows, {2,3} -> g-rows; per-wave acc = 64 f32 -> total
// ~120 regs -> 4 waves/SIMD (2x latency hiding at every barrier/ds_read).
// LDS 128 KiB = 2 bufs x (A 256x64 + B 256x64). Per buf (shorts):
// A0=[0,8192) rows 0-127(a), A1=[8192,16384) rows 128-255(g),
// B0=[16384,24576), B1=[24576,32768).
// Pipeline (counted vmcnt, never 0 in steady state); per iter (2 tiles):
//  R1: STAGE t1.A(2) ; vmcnt(2) [confirms buf0=t0] ; BAR; ds_read buf0 ks0; 16 MFMA; BAR
//  R2: ds_read buf0 ks1 ; STAGE t1.B(2) ; BAR; MFMA; BAR
//  R3: STAGE tn0.A(2) ; vmcnt(2) [confirms buf1=t1] ; BAR; ds_read buf1 ks0; MFMA; BAR
//  R4: ds_read buf1 ks1 ; STAGE tn0.B(2) ; BAR; MFMA; BAR
// Ledger (per-thread, 1 load/STAGE): enter R1 with 4 outstanding (t0);
// R1 +2 -> 6, wait(2) drains t0's 4; R2 +2 -> 4; R3 +2 -> 6, wait(2) drains
// t1's 4; R4 +2 -> 4. Overwrite safety: each region's last read precedes its
// re-stage by >=1 post-MMA barrier (buf0 read R1/R2, restaged R3/R4; buf1
// read R3/R4, restaged next R1/R2). Epilogue: g-waves park raw accg in LDS
// (fp32, XOR-swizzled), sync, a-waves combine + GLU + store. Per-element
// accumulation order identical to prior rounds -> bitwise-identical output.
#define BAR       asm volatile("s_barrier" ::: "memory")
#define WAITV2    asm volatile("s_waitcnt vmcnt(2)" ::: "memory")
#define WAITV0    asm volatile("s_waitcnt vmcnt(0)" ::: "memory")

#define STAGE(srcp, buf, regionShorts, koff)                                   \
    gload16((srcp) + (koff), smem + (buf) * 32768 + (regionShorts) + tid * 8)

#define LDFR(sb, rbarr, off, dst) do {                                         \
    _Pragma("unroll")                                                          \
    for (int _i = 0; _i < 4; _i++)                                             \
        dst[_i] = *(const short8x*)((sb) + rbarr[_i] + (off));                 \
} while (0)

#define MMA16(afr, br) do {                                                    \
    __builtin_amdgcn_s_setprio(1);                                             \
    _Pragma("unroll")                                                          \
    for (int _i = 0; _i < 4; _i++)                                             \
        _Pragma("unroll")                                                      \
        for (int _j = 0; _j < 4; _j++)                                         \
            acc[_i][_j] = __builtin_amdgcn_mfma_f32_16x16x32_bf16(             \
                afr[_i], br[_j], acc[_i][_j], 0, 0, 0);                        \
    __builtin_amdgcn_s_setprio(0);                                             \
} while (0)

__global__ __launch_bounds__(1024) void k_gemm(const unsigned short* __restrict__ Wbf,
                                               const unsigned short* __restrict__ Vt,
                                               const float* __restrict__ bvec,
                                               float* __restrict__ out) {
    __shared__ unsigned short smem[65536];       // 128 KiB: buf b at b*32768 shorts
    int tid  = threadIdx.x;
    int flat = blockIdx.x;                       // 512 blocks, nwg%8==0
    int swz  = (flat & 7) * 64 + (flat >> 3);    // XCD-contiguous chunks of 64
    int m0   = (swz & 7) * 128;                  // 8 m-blocks
    int n0   = (swz >> 3) * 256;                 // 64 n-panels

    // staging: each half-tile = 1024 chunks of 16B, 1 chunk/thread.
    // LDS slot s of row r holds global k-chunk s^(r&7); dest linear.
    int r = tid >> 3, s = tid & 7;
    int kg = s ^ (r & 7);
    const unsigned short* sA0 = Wbf + (int64_t)(m0 + r) * HD + kg * 8;
    const unsigned short* sA1 = Wbf + (int64_t)(1024 + m0 + r) * HD + kg * 8;
    const unsigned short* sB0 = Vt + (int64_t)(n0 + r) * HD + kg * 8;
    const unsigned short* sB1 = Vt + (int64_t)(n0 + 128 + r) * HD + kg * 8;

    int lane = tid & 63;
    int wid  = tid >> 6;                         // 0..15
    int wm = wid >> 2;                           // 0..3 (0,1: a-rows; 2,3: g-rows)
    int wn = wid & 3;                            // 0..3
    int l15 = lane & 15, quad = lane >> 4;
    int xr = l15 & 7;

    int rb[4], rbb[4];                           // row bases (shorts, per buf)
#pragma unroll
    for (int i = 0; i < 4; i++) {
        int zr = wm * 64 + i * 16 + l15;         // 0..255 (A region rows)
        rb[i] = zr * 64;
        int cb = wn * 64 + i * 16 + l15;         // 0..255 (B cols)
        rbb[i] = 16384 + cb * 64;
    }
    int off0 = (quad ^ xr) * 8;                  // ks=0 swizzled slot
    int off1 = ((4 + quad) ^ xr) * 8;            // ks=1

    const unsigned short* sb0 = smem;
    const unsigned short* sb1 = smem + 32768;

    float4x acc[4][4];                           // this wave's a-or-g quadrant
#pragma unroll
    for (int i = 0; i < 4; i++)
#pragma unroll
        for (int j = 0; j < 4; j++) acc[i][j] = (float4x){0.f, 0.f, 0.f, 0.f};

    short8x fr[4], br[4];

    // prologue: tile0 -> buf0 (4 loads outstanding)
    STAGE(sA0, 0, 0, 0); STAGE(sA1, 0, 8192, 0);
    STAGE(sB0, 0, 16384, 0); STAGE(sB1, 0, 24576, 0);

    for (int i = 0; i < 7; i++) {
        int o1 = (2 * i + 1) * 64, o2 = (2 * i + 2) * 64;
        // R1: prefetch t1.A -> buf1; confirm buf0=t0; compute t0/ks0
        STAGE(sA0, 1, 0, o1); STAGE(sA1, 1, 8192, o1);
        WAITV2; BAR;
        LDFR(sb0, rb, off0, fr); LDFR(sb0, rbb, off0, br);
        MMA16(fr, br); BAR;
        // R2: compute t0/ks1; prefetch t1.B -> buf1
        LDFR(sb0, rb, off1, fr); LDFR(sb0, rbb, off1, br);
        STAGE(sB0, 1, 16384, o1); STAGE(sB1, 1, 24576, o1);
        BAR; MMA16(fr, br); BAR;
        // R3: prefetch tn0.A -> buf0; confirm buf1=t1; compute t1/ks0
        STAGE(sA0, 0, 0, o2); STAGE(sA1, 0, 8192, o2);
        WAITV2; BAR;
        LDFR(sb1, rb, off0, fr); LDFR(sb1, rbb, off0, br);
        MMA16(fr, br); BAR;
        // R4: compute t1/ks1; prefetch tn0.B -> buf0
        LDFR(sb1, rb, off1, fr); LDFR(sb1, rbb, off1, br);
        STAGE(sB0, 0, 16384, o2); STAGE(sB1, 0, 24576, o2);
        BAR; MMA16(fr, br); BAR;
    }
    // tail: tiles 14 (buf0) and 15 (buf1); stage only t15
    {
        STAGE(sA0, 1, 0, 960); STAGE(sA1, 1, 8192, 960);
        WAITV2; BAR;
        LDFR(sb0, rb, off0, fr); LDFR(sb0, rbb, off0, br);
        MMA16(fr, br); BAR;

        LDFR(sb0, rb, off1, fr); LDFR(sb0, rbb, off1, br);
        STAGE(sB0, 1, 16384, 960); STAGE(sB1, 1, 24576, 960);
        BAR; MMA16(fr, br); BAR;

        WAITV0; BAR;
        LDFR(sb1, rb, off0, fr); LDFR(sb1, rbb, off0, br);
        MMA16(fr, br); BAR;

        LDFR(sb1, rb, off1, fr); LDFR(sb1, rbb, off1, br);
        MMA16(fr, br);
    }

    // epilogue: g-waves park raw accg in LDS (fp32), a-waves combine + GLU.
    // gl[col][rowblock]: float4 (rows 4*srb..+3 of col) at
    // gl + col*128 + ((srb ^ (col&15))<<2); srb in 0..31. 32768 floats = 128 KiB.
    __syncthreads();
    float* gl = (float*)smem;
    if (wm >= 2) {
#pragma unroll
        for (int i = 0; i < 4; i++) {
            int srb = (wm - 2) * 16 + i * 4 + quad;
#pragma unroll
            for (int j = 0; j < 4; j++) {
                int col = wn * 64 + j * 16 + l15;
                *(float4x*)(gl + col * 128 + ((srb ^ (col & 15)) << 2)) = acc[i][j];
            }
        }
    }
    __syncthreads();
    if (wm < 2) {
        int b = n0 >> 12;
#pragma unroll
        for (int i = 0; i < 4; i++) {
            int h0 = m0 + wm * 64 + i * 16 + quad * 4;
            int srb = wm * 16 + i * 4 + quad;
            float ba[4], bg[4];
#pragma unroll
            for (int rr = 0; rr < 4; rr++) { ba[rr] = bvec[h0 + rr]; bg[rr] = bvec[1024 + h0 + rr]; }
#pragma unroll
            for (int j = 0; j < 4; j++) {
                int col = wn * 64 + j * 16 + l15;
                float4x gv = *(const float4x*)(gl + col * 128 + ((srb ^ (col & 15)) << 2));
                int n = n0 + col;
                int l = n & (LD - 1);
                float* op = out + ((int64_t)b * HD + h0) * LD + l;
#pragma unroll
                for (int rr = 0; rr < 4; rr++) {
                    float av = acc[i][j][rr] + ba[rr];
                    float gvv = gv[rr] + bg[rr];
                    op[(int64_t)rr * LD] = av / (1.0f + __expf(-gvv));
                }
            }
        }
    }
}

extern "C" void kernel_launch(void* const* d_in, const int* in_sizes, int n_in,
                              void* d_out, int out_size, void* d_ws, size_t ws_size,
                              hipStream_t stream) {
    const float* u    = (const float*)d_in[0];   // (4,1024,4096)
    const float* kern = (const float*)d_in[1];   // (1,1024,8192)
    const float* Dv   = (const float*)d_in[2];   // (1,1024)
    const float* W    = (const float*)d_in[3];   // (2048,1024)
    const float* bv   = (const float*)d_in[4];   // (2048,)
    float* out = (float*)d_out;                  // (4,1024,4096)

    char* ws = (char*)d_ws;
    int* ntaps = (int*)ws;                                   // [0,64)
    int* cnt64 = (int*)(ws + 64);                            // 16 ints
    Tap* taps  = (Tap*)(ws + 256);                           // 512 KiB cap
    unsigned short* Wbf = (unsigned short*)(ws + (1 << 20)); // 4 MiB
    unsigned short* Vt  = (unsigned short*)(ws + (8 << 20)); // 32 MiB

    hipMemsetAsync(ws, 0, 256, stream);
    hipLaunchKernelGGL(k_pv,   dim3(7168),        dim3(256), 0, stream,
                       u, kern, Dv, W, ntaps, cnt64, taps, Wbf, Vt);
    hipLaunchKernelGGL(k_fix,  dim3(16, 64, 4),   dim3(256), 0, stream,
                       u, Dv, ntaps, cnt64, taps, Vt);
    hipLaunchKernelGGL(k_gemm, dim3(512),         dim3(1024), 0, stream, Wbf, Vt, bv, out);
}